// Round 1
// baseline (79.559 us; speedup 1.0000x reference)
//
#include <hip/hip_runtime.h>

// CenterLoss: loss = (1/B) * sum_b clip(||x_b - c_{l_b}||^2, 1e-12, 1e12)
//             + (C-1)*1e-12   (reference clamps the B*(C-1) masked zeros up
//             to 1e-12 before summing; exact, though far below tolerance)
//
// x: [B=8192, D=256] f32, labels: [B] int, centers: [C=10000, D=256] f32.
//
// R3 design: the rocprof top-5 showed the timed window is dominated by the
// harness's 256 MiB d_ws re-poison fill (~42 us @ 79% HBM peak), not our
// kernels. So: USE NO WORKSPACE AT ALL.
//   - one fused kernel, one sample per wave (8192 waves = 1024 blocks x 512
//     thr = max occupancy; label->center dependent chain hidden by TLP)
//   - wave shfl-reduce -> 8-wave LDS collect -> ONE atomicAdd per block into
//     out[0] (1024 same-address f32 atomics, pipelined in TCC, <1 us)
//   - out[0] zero-init via 4-byte hipMemsetAsync (graph-capturable)
//   - per-block partial pre-scaled by 1/B = 2^-13 (exact), so out[0] ends as
//     the final loss; block 0 adds the (C-1)*1e-12 clamp-floor term once.
// Accumulation order across blocks is nondeterministic but all terms are
// positive (no cancellation): expected |delta| ~1e-4 on a loss of ~512.

#define TPB 512                         // 8 waves per block
#define WPB (TPB / 64)

__global__ __launch_bounds__(TPB) void centerloss_fused(
    const float* __restrict__ x,
    const int* __restrict__ labels,
    const float* __restrict__ centers,
    float* __restrict__ out,
    int B, int C, float invB)
{
    const int lane = threadIdx.x & 63;
    const int wid  = threadIdx.x >> 6;
    const int b    = (int)((blockIdx.x * TPB + threadIdx.x) >> 6);  // global wave id

    float v = 0.0f;
    const bool valid = (b < B);
    if (valid) {
        const int lbl = labels[b];                                  // wave-uniform
        const float4 xv = ((const float4*)(x       + (size_t)b   * 256))[lane];
        const float4 cv = ((const float4*)(centers + (size_t)lbl * 256))[lane];

        // per-lane contribution to ||x||^2 + ||c||^2 - 2<x,c>
        // (expanded form kept bit-identical to the verified R2 kernel)
        v  = xv.x * xv.x + xv.y * xv.y + xv.z * xv.z + xv.w * xv.w;
        v += cv.x * cv.x + cv.y * cv.y + cv.z * cv.z + cv.w * cv.w;
        v -= 2.0f * (xv.x * cv.x + xv.y * cv.y + xv.z * cv.z + xv.w * cv.w);
    }

    // wave-level sum (64 lanes)
    #pragma unroll
    for (int off = 32; off > 0; off >>= 1)
        v += __shfl_down(v, off, 64);

    __shared__ float s[WPB];
    if (lane == 0)
        s[wid] = valid ? fminf(fmaxf(v, 1e-12f), 1e12f) * invB : 0.0f;  // *2^-13: exact
    __syncthreads();

    if (threadIdx.x == 0) {
        float t = 0.0f;
        #pragma unroll
        for (int i = 0; i < WPB; ++i) t += s[i];
        if (blockIdx.x == 0)
            t += (float)((double)(C - 1) * 1e-12);   // clamp floor of masked zeros
        atomicAdd(out, t);                            // device-scope, 1 per block
    }
}

extern "C" void kernel_launch(void* const* d_in, const int* in_sizes, int n_in,
                              void* d_out, int out_size, void* d_ws, size_t ws_size,
                              hipStream_t stream)
{
    const float* x       = (const float*)d_in[0];
    const int*   labels  = (const int*)d_in[1];
    const float* centers = (const float*)d_in[2];

    const int B = in_sizes[1];                 // 8192
    const int D = in_sizes[0] / B;             // 256 (layout assumed by kernel)
    const int C = in_sizes[2] / D;             // 10000

    float* out = (float*)d_out;

    (void)d_ws; (void)ws_size;                 // deliberately unused (see header)

    hipMemsetAsync(out, 0, sizeof(float), stream);   // capturable memset node

    const int nblocks = (B * 64 + TPB - 1) / TPB;    // one wave per sample
    centerloss_fused<<<nblocks, TPB, 0, stream>>>(x, labels, centers, out,
                                                  B, C, 1.0f / (float)B);
}